// Round 4
// baseline (190.517 us; speedup 1.0000x reference)
//
#include <hip/hip_runtime.h>
#include <hip/hip_bf16.h>

#define LN_EPS 1e-5f

typedef __attribute__((ext_vector_type(8))) short bf16x8_t;
typedef __attribute__((ext_vector_type(4))) float f32x4_t;
typedef __attribute__((ext_vector_type(4))) unsigned short u16x4_t;

__device__ inline unsigned short f2bf(float f) {
    union { float f; unsigned int u; } v; v.f = f;
    unsigned int r = v.u + 0x7fffu + ((v.u >> 16) & 1u);
    return (unsigned short)(r >> 16);
}

// pack 4 floats -> 4 bf16 via v_cvt_pk_bf16_f32
__device__ inline u16x4_t pk4(float a, float b, float c, float d) {
    union { u16x4_t v; __hip_bfloat162 h[2]; } u;
    u.h[0] = __float22bfloat162_rn(float2{a, b});
    u.h[1] = __float22bfloat162_rn(float2{c, d});
    return u.v;
}

// Fragment-layout index for a [ROWS][KD] matrix stored as MFMA A/B fragments:
// tile (row>>4, k>>5) is 512 contiguous u16; lane=((k>>3)&3)*16+(row&15), j=k&7.
__device__ inline size_t fragidx(int row, int k, int KC) {
    return ((size_t)((row >> 4) * KC + (k >> 5))) * 512 +
           (((k >> 3) & 3) * 16 + (row & 15)) * 8 + (k & 7);
}

// ---------------------------------------------------------------------------
__global__ void k_prep_w(const float* __restrict__ qW, const float* __restrict__ kvW,
                         const float* __restrict__ projW, const float* __restrict__ srW,
                         unsigned short* __restrict__ qWs, unsigned short* __restrict__ kvWs,
                         unsigned short* __restrict__ projWs, unsigned short* __restrict__ srWs) {
    int i = blockIdx.x * 256 + threadIdx.x;
    if (i < 16384) {
        int n = i & 127, k = i >> 7;
        qWs[fragidx(n, k, 4)] = f2bf(qW[k * 128 + n]);
    } else if (i < 49152) {
        int j = i - 16384; int n = j & 255, k = j >> 8;
        kvWs[fragidx(n, k, 4)] = f2bf(kvW[k * 256 + n]);
    } else if (i < 65536) {
        int j = i - 49152; int n = j & 127, k = j >> 7;
        projWs[fragidx(n, k, 4)] = f2bf(projW[k * 128 + n]);
    } else {
        int j = i - 65536; int n = j >> 9, rem = j & 511, q = rem >> 7, c = rem & 127;
        srWs[fragidx(n, q * 128 + c, 16)] = f2bf(srW[n * 512 + c * 4 + q]);
    }
}

// ---------------------------------------------------------------------------
// x fp32 -> xsw (frags [32768][128]) AND Psw (conv patch frags [8192][512])
__global__ void k_prep_x(const float* __restrict__ x, unsigned short* __restrict__ xsw,
                         unsigned short* __restrict__ Psw) {
    int i = blockIdx.x * 256 + threadIdx.x;
    int c4 = i & 31;
    int row = i >> 5;
    float4 v = *(const float4*)(x + (size_t)row * 128 + c4 * 4);
    u16x4_t o = pk4(v.x, v.y, v.z, v.w);
    int ch = c4 * 4;
    *(u16x4_t*)(xsw + fragidx(row, ch, 4)) = o;
    int b = row >> 13, n = row & 8191;
    int hf = n >> 12, rem = n & 4095;
    int y = rem >> 6, xc = rem & 63;
    int oy = y >> 1, ky = y & 1, ox = xc >> 1, kx = xc & 1;
    int q = ky * 2 + kx;
    int pos = b * 2048 + hf * 1024 + oy * 32 + ox;
    *(u16x4_t*)(Psw + fragidx(pos, q * 128 + ch, 16)) = o;
}

// ---------------------------------------------------------------------------
// Transposed MFMA GEMM: Y^T = Wf(A) x Xf(B). Block = 128 data rows x 128 feats.
// Wave w: row-tiles {w*2, w*2+1}; lane's 4 acc values = 4 consecutive features
// of ONE data row -> vector epilogue stores.
// MODE 0: fp32 row-major out [R][128].  MODE 1: Q frags (*0.1803).
// MODE 2: K frags.  MODE 3: fused LayerNorm -> xkv frags.
template <int KC, int MODE>
__global__ __launch_bounds__(256)
void k_gemmT(const unsigned short* __restrict__ Wf, const unsigned short* __restrict__ Xf,
             const float* __restrict__ bias, const float* __restrict__ lnW,
             const float* __restrict__ lnB, void* __restrict__ out) {
    const int t = threadIdx.x, w = t >> 6, lane = t & 63;
    const int col = lane & 15, quad = lane >> 4;
    const int rt0 = blockIdx.x * 8 + w * 2;
    const unsigned short* xp = Xf + (size_t)rt0 * KC * 512 + lane * 8;
    const unsigned short* wp = Wf + lane * 8;
    f32x4_t acc[8][2] = {};
    #pragma unroll
    for (int kc = 0; kc < KC; kc++) {
        bf16x8_t x0 = *(const bf16x8_t*)(xp + (size_t)kc * 512);
        bf16x8_t x1 = *(const bf16x8_t*)(xp + (size_t)(KC + kc) * 512);
        #pragma unroll
        for (int nt = 0; nt < 8; nt++) {
            bf16x8_t wf = *(const bf16x8_t*)(wp + (size_t)(nt * KC + kc) * 512);
            acc[nt][0] = __builtin_amdgcn_mfma_f32_16x16x32_bf16(wf, x0, acc[nt][0], 0, 0, 0);
            acc[nt][1] = __builtin_amdgcn_mfma_f32_16x16x32_bf16(wf, x1, acc[nt][1], 0, 0, 0);
        }
    }
    if constexpr (MODE == 3) {
        // add bias, then LayerNorm across the 128 features of each data row
        #pragma unroll
        for (int nt = 0; nt < 8; nt++) {
            float4 bs = *(const float4*)(bias + nt * 16 + quad * 4);
            #pragma unroll
            for (int ct = 0; ct < 2; ct++) {
                acc[nt][ct][0] += bs.x; acc[nt][ct][1] += bs.y;
                acc[nt][ct][2] += bs.z; acc[nt][ct][3] += bs.w;
            }
        }
        #pragma unroll
        for (int ct = 0; ct < 2; ct++) {
            float s = 0.f, ss = 0.f;
            #pragma unroll
            for (int nt = 0; nt < 8; nt++)
                #pragma unroll
                for (int r = 0; r < 4; r++) {
                    float v = acc[nt][ct][r];
                    s += v; ss += v * v;
                }
            s += __shfl_xor(s, 16, 64);  s += __shfl_xor(s, 32, 64);
            ss += __shfl_xor(ss, 16, 64); ss += __shfl_xor(ss, 32, 64);
            float mean = s * (1.0f / 128.0f);
            float var = ss * (1.0f / 128.0f) - mean * mean;
            float rs = rsqrtf(var + LN_EPS);
            int p = (rt0 + ct) * 16 + col;
            #pragma unroll
            for (int nt = 0; nt < 8; nt++) {
                float4 g = *(const float4*)(lnW + nt * 16 + quad * 4);
                float4 be = *(const float4*)(lnB + nt * 16 + quad * 4);
                u16x4_t o = pk4((acc[nt][ct][0] - mean) * rs * g.x + be.x,
                                (acc[nt][ct][1] - mean) * rs * g.y + be.y,
                                (acc[nt][ct][2] - mean) * rs * g.z + be.z,
                                (acc[nt][ct][3] - mean) * rs * g.w + be.w);
                *(u16x4_t*)((unsigned short*)out +
                            ((size_t)((p >> 4) * 4 + (nt >> 1))) * 512 +
                            (((nt & 1) * 2 + (quad >> 1)) * 16 + (p & 15)) * 8 +
                            (quad & 1) * 4) = o;
            }
        }
    } else {
        #pragma unroll
        for (int nt = 0; nt < 8; nt++) {
            float4 bs = *(const float4*)(bias + nt * 16 + quad * 4);
            #pragma unroll
            for (int ct = 0; ct < 2; ct++) {
                int p = (rt0 + ct) * 16 + col;
                float v0 = acc[nt][ct][0] + bs.x, v1 = acc[nt][ct][1] + bs.y;
                float v2 = acc[nt][ct][2] + bs.z, v3 = acc[nt][ct][3] + bs.w;
                if (MODE == 0) {
                    float4 o = { v0, v1, v2, v3 };
                    *(float4*)((float*)out + (size_t)p * 128 + nt * 16 + quad * 4) = o;
                } else if (MODE == 1) {   // Q frags, scale*log2e folded
                    const float sc = 0.125f * 1.44269504089f;
                    int bh = (p >> 13) * 2 + (nt >> 2), n = p & 8191;
                    u16x4_t o = pk4(v0 * sc, v1 * sc, v2 * sc, v3 * sc);
                    *(u16x4_t*)((unsigned short*)out +
                                ((size_t)(bh * 512 + (n >> 4)) * 2 + ((nt >> 1) & 1)) * 512 +
                                (((nt & 1) * 2 + (quad >> 1)) * 16 + (n & 15)) * 8 +
                                (quad & 1) * 4) = o;
                } else {                  // MODE 2: K frags
                    int bh = (p >> 11) * 2 + (nt >> 2), m = p & 2047;
                    u16x4_t o = pk4(v0, v1, v2, v3);
                    *(u16x4_t*)((unsigned short*)out +
                                ((size_t)(bh * 128 + (m >> 4)) * 2 + ((nt >> 1) & 1)) * 512 +
                                (((nt & 1) * 2 + (quad >> 1)) * 16 + (m & 15)) * 8 +
                                (quad & 1) * 4) = o;
                }
            }
        }
    }
}

// ---------------------------------------------------------------------------
// V-half of kv projection, NORMAL orientation (lane's 4 accs = 4 consecutive
// keys m of one feature d -> u16x4 into vsw V^T frag layout).
// Block: 32 rows x 128 V-features (4 waves over features). Grid 256.
__global__ __launch_bounds__(256)
void k_gemmV(const unsigned short* __restrict__ Xf, const unsigned short* __restrict__ kvWs,
             const float* __restrict__ kvb, unsigned short* __restrict__ vsw) {
    const int t = threadIdx.x, w = t >> 6, lane = t & 63;
    const int col = lane & 15, quad = lane >> 4;
    const int rt0 = blockIdx.x * 2;
    const unsigned short* ap = Xf + (size_t)rt0 * 4 * 512 + lane * 8;
    const unsigned short* wp = kvWs + (size_t)(8 + w * 2) * 4 * 512 + lane * 8;
    f32x4_t acc[2][2] = {};
    #pragma unroll
    for (int kc = 0; kc < 4; kc++) {
        bf16x8_t a0 = *(const bf16x8_t*)(ap + (size_t)kc * 512);
        bf16x8_t a1 = *(const bf16x8_t*)(ap + (size_t)(4 + kc) * 512);
        bf16x8_t b0 = *(const bf16x8_t*)(wp + (size_t)kc * 512);
        bf16x8_t b1 = *(const bf16x8_t*)(wp + (size_t)(4 + kc) * 512);
        acc[0][0] = __builtin_amdgcn_mfma_f32_16x16x32_bf16(a0, b0, acc[0][0], 0, 0, 0);
        acc[0][1] = __builtin_amdgcn_mfma_f32_16x16x32_bf16(a0, b1, acc[0][1], 0, 0, 0);
        acc[1][0] = __builtin_amdgcn_mfma_f32_16x16x32_bf16(a1, b0, acc[1][0], 0, 0, 0);
        acc[1][1] = __builtin_amdgcn_mfma_f32_16x16x32_bf16(a1, b1, acc[1][1], 0, 0, 0);
    }
    #pragma unroll
    for (int rt = 0; rt < 2; rt++) {
        #pragma unroll
        for (int ct = 0; ct < 2; ct++) {
            int d = (w * 2 + ct) * 16 + col;        // 0..127 across 2 heads
            int h = d >> 6, dd = d & 63;
            float bs = kvb[128 + d];
            int gr0 = (rt0 + rt) * 16 + quad * 4;
            int b = gr0 >> 11, m0 = gr0 & 2047;
            int bh = b * 2 + h, dt = dd >> 4;
            u16x4_t o = pk4(acc[rt][ct][0] + bs, acc[rt][ct][1] + bs,
                            acc[rt][ct][2] + bs, acc[rt][ct][3] + bs);
            *(u16x4_t*)(vsw + ((size_t)((bh * 4 + dt) * 64 + (m0 >> 5))) * 512 +
                        (((m0 >> 3) & 3) * 16 + (dd & 15)) * 8 + (m0 & 7)) = o;
        }
    }
}

// ---------------------------------------------------------------------------
// MFMA attention (fragment-layout operands, transposed-S, exp2-based softmax,
// l via ones-MFMA). grid (32, 2, 8), block 256.
__global__ __launch_bounds__(256, 2)
void k_attn3(const unsigned short* __restrict__ qsw,
             const unsigned short* __restrict__ ksw,
             const unsigned short* __restrict__ vsw,
             unsigned short* __restrict__ aoutsw) {
    const int bh = blockIdx.z, mod = blockIdx.y, bx = blockIdx.x;
    const int t = threadIdx.x, w = t >> 6, lane = t & 63;
    const int col = lane & 15, quad = lane >> 4;
    const int qbase = mod * 4096 + bx * 128 + w * 32;

    __shared__ unsigned short pp[4][2][16][72];

    bf16x8_t qf[2][2];
    {
        const unsigned short* qp =
            qsw + ((size_t)(bh * 512 + (qbase >> 4)) * 2) * 512 + lane * 8;
        qf[0][0] = *(const bf16x8_t*)(qp);
        qf[0][1] = *(const bf16x8_t*)(qp + 512);
        qf[1][0] = *(const bf16x8_t*)(qp + 1024);
        qf[1][1] = *(const bf16x8_t*)(qp + 1536);
    }
    const unsigned short* kp0 =
        ksw + ((size_t)(bh * 128 + (1 - mod) * 64) * 2) * 512 + lane * 8;
    const unsigned short* vp0 =
        vsw + ((size_t)(bh * 4) * 64 + (1 - mod) * 32) * 512 + lane * 8;

    const bf16x8_t ones = { 0x3F80, 0x3F80, 0x3F80, 0x3F80,
                            0x3F80, 0x3F80, 0x3F80, 0x3F80 };

    f32x4_t O[2][4] = {};
    f32x4_t accl[2] = {};

    bf16x8_t kcur[8];
    #pragma unroll
    for (int i = 0; i < 8; i++)
        kcur[i] = *(const bf16x8_t*)(kp0 + (size_t)i * 512);

    for (int kt = 0; kt < 16; kt++) {
        bf16x8_t vcur[8];
        #pragma unroll
        for (int dt = 0; dt < 4; dt++) {
            vcur[dt * 2 + 0] = *(const bf16x8_t*)(vp0 + ((size_t)dt * 64 + kt * 2 + 0) * 512);
            vcur[dt * 2 + 1] = *(const bf16x8_t*)(vp0 + ((size_t)dt * 64 + kt * 2 + 1) * 512);
        }
        const int ktn = (kt + 1) & 15;
        bf16x8_t knext[8];
        #pragma unroll
        for (int i = 0; i < 8; i++)
            knext[i] = *(const bf16x8_t*)(kp0 + (size_t)(ktn * 8 + i) * 512);

        f32x4_t ST[2][4];
        #pragma unroll
        for (int qt = 0; qt < 2; qt++)
            #pragma unroll
            for (int nb = 0; nb < 4; nb++) {
                f32x4_t s = {};
                s = __builtin_amdgcn_mfma_f32_16x16x32_bf16(kcur[nb * 2 + 0], qf[qt][0], s, 0, 0, 0);
                s = __builtin_amdgcn_mfma_f32_16x16x32_bf16(kcur[nb * 2 + 1], qf[qt][1], s, 0, 0, 0);
                ST[qt][nb] = s;
            }
        #pragma unroll
        for (int qt = 0; qt < 2; qt++)
            #pragma unroll
            for (int nb = 0; nb < 4; nb++) {
                u16x4_t pk = pk4(exp2f(ST[qt][nb][0]), exp2f(ST[qt][nb][1]),
                                 exp2f(ST[qt][nb][2]), exp2f(ST[qt][nb][3]));
                *(u16x4_t*)(&pp[w][qt][col][nb * 16 + quad * 4]) = pk;
            }
        bf16x8_t pb[2][2];
        #pragma unroll
        for (int qt = 0; qt < 2; qt++) {
            pb[qt][0] = *(const bf16x8_t*)(&pp[w][qt][col][quad * 8]);
            pb[qt][1] = *(const bf16x8_t*)(&pp[w][qt][col][32 + quad * 8]);
        }
        #pragma unroll
        for (int qt = 0; qt < 2; qt++) {
            accl[qt] = __builtin_amdgcn_mfma_f32_16x16x32_bf16(ones, pb[qt][0], accl[qt], 0, 0, 0);
            accl[qt] = __builtin_amdgcn_mfma_f32_16x16x32_bf16(ones, pb[qt][1], accl[qt], 0, 0, 0);
        }
        #pragma unroll
        for (int dt = 0; dt < 4; dt++)
            #pragma unroll
            for (int qt = 0; qt < 2; qt++) {
                O[qt][dt] = __builtin_amdgcn_mfma_f32_16x16x32_bf16(vcur[dt * 2 + 0], pb[qt][0],
                                                                   O[qt][dt], 0, 0, 0);
                O[qt][dt] = __builtin_amdgcn_mfma_f32_16x16x32_bf16(vcur[dt * 2 + 1], pb[qt][1],
                                                                   O[qt][dt], 0, 0, 0);
            }
        #pragma unroll
        for (int i = 0; i < 8; i++) kcur[i] = knext[i];
    }

    const int b = bh >> 1, h = bh & 1;
    #pragma unroll
    for (int qt = 0; qt < 2; qt++) {
        float rl = 1.0f / accl[qt][0];
        int n_g = b * 8192 + qbase + qt * 16 + col;
        int rt_a = n_g >> 4;
        #pragma unroll
        for (int dt = 0; dt < 4; dt++) {
            int kc_a = h * 2 + (dt >> 1);
            int quad_a = (dt & 1) * 2 + (quad >> 1);
            int j0 = (quad & 1) * 4;
            u16x4_t o = pk4(O[qt][dt][0] * rl, O[qt][dt][1] * rl,
                            O[qt][dt][2] * rl, O[qt][dt][3] * rl);
            *(u16x4_t*)(aoutsw + ((size_t)(rt_a * 4 + kc_a)) * 512 +
                        (quad_a * 16 + col) * 8 + j0) = o;
        }
    }
}

// ---------------------------------------------------------------------------
extern "C" void kernel_launch(void* const* d_in, const int* in_sizes, int n_in,
                              void* d_out, int out_size, void* d_ws, size_t ws_size,
                              hipStream_t stream) {
    const float* x     = (const float*)d_in[0];
    const float* qW    = (const float*)d_in[1];
    const float* qb    = (const float*)d_in[2];
    const float* kvW   = (const float*)d_in[3];
    const float* kvb   = (const float*)d_in[4];
    const float* projW = (const float*)d_in[5];
    const float* projb = (const float*)d_in[6];
    const float* srW   = (const float*)d_in[7];
    const float* srb   = (const float*)d_in[8];
    const float* lnW   = (const float*)d_in[9];
    const float* lnB   = (const float*)d_in[10];

    char* ws = (char*)d_ws;
    unsigned short* qWs    = (unsigned short*)(ws + 0);
    unsigned short* kvWs   = (unsigned short*)(ws + 32768);
    unsigned short* projWs = (unsigned short*)(ws + 98304);
    unsigned short* srWs   = (unsigned short*)(ws + 131072);
    unsigned short* xsw    = (unsigned short*)(ws + 262144);    // 8 MB
    unsigned short* Psw    = (unsigned short*)(ws + 8650752);   // 8 MB
    unsigned short* qsw    = (unsigned short*)(ws + 17039360);  // 8 MB
    unsigned short* ksw    = (unsigned short*)(ws + 25427968);  // 2 MB
    unsigned short* vsw    = (unsigned short*)(ws + 27525120);  // 2 MB
    unsigned short* xkvsw  = (unsigned short*)(ws + 29622272);  // 2 MB
    unsigned short* aoutsw = (unsigned short*)(ws + 31719424);  // 8 MB

    k_prep_w<<<dim3(512), dim3(256), 0, stream>>>(qW, kvW, projW, srW,
                                                  qWs, kvWs, projWs, srWs);
    k_prep_x<<<dim3(4096), dim3(256), 0, stream>>>(x, xsw, Psw);
    // q projection (transposed, scale*log2e folded) -> q fragments
    k_gemmT<4, 1><<<dim3(256), dim3(256), 0, stream>>>(qWs, xsw, qb, nullptr, nullptr,
                                                       (void*)qsw);
    // SR conv + fused LayerNorm -> xkv fragments
    k_gemmT<16, 3><<<dim3(64), dim3(256), 0, stream>>>(srWs, Psw, srb, lnW, lnB,
                                                       (void*)xkvsw);
    // K projection (transposed) -> K fragments
    k_gemmT<4, 2><<<dim3(64), dim3(256), 0, stream>>>(kvWs, xkvsw, kvb, nullptr, nullptr,
                                                      (void*)ksw);
    // V projection (normal) -> V^T fragments
    k_gemmV<<<dim3(256), dim3(256), 0, stream>>>(xkvsw, kvWs, kvb, vsw);
    // attention -> proj-operand fragments
    k_attn3<<<dim3(32, 2, 8), dim3(256), 0, stream>>>(qsw, ksw, vsw, aoutsw);
    // output projection (transposed) -> d_out fp32 row-major
    k_gemmT<4, 0><<<dim3(256), dim3(256), 0, stream>>>(projWs, aoutsw, projb, nullptr,
                                                       nullptr, d_out);
}

// Round 5
// 149.110 us; speedup vs baseline: 1.2777x; 1.2777x over previous
//
#include <hip/hip_runtime.h>
#include <hip/hip_bf16.h>

#define LN_EPS 1e-5f

typedef __attribute__((ext_vector_type(8))) short bf16x8_t;
typedef __attribute__((ext_vector_type(4))) float f32x4_t;
typedef __attribute__((ext_vector_type(4))) unsigned short u16x4_t;

#define MFMA16(a, b, c) __builtin_amdgcn_mfma_f32_16x16x32_bf16(a, b, c, 0, 0, 0)

__device__ inline unsigned short f2bf(float f) {
    union { float f; unsigned int u; } v; v.f = f;
    unsigned int r = v.u + 0x7fffu + ((v.u >> 16) & 1u);
    return (unsigned short)(r >> 16);
}

__device__ inline u16x4_t pk4(float a, float b, float c, float d) {
    union { u16x4_t v; __hip_bfloat162 h[2]; } u;
    u.h[0] = __float22bfloat162_rn(float2{a, b});
    u.h[1] = __float22bfloat162_rn(float2{c, d});
    return u.v;
}

// Fragment-layout index for [ROWS][KD] stored as MFMA fragments:
// tile (row>>4, k>>5) = 512 contiguous u16; lane=((k>>3)&3)*16+(row&15), j=k&7.
__device__ inline size_t fragidx(int row, int k, int KC) {
    return ((size_t)((row >> 4) * KC + (k >> 5))) * 512 +
           (((k >> 3) & 3) * 16 + (row & 15)) * 8 + (k & 7);
}

// ---------------------------------------------------------------------------
__global__ void k_prep_w(const float* __restrict__ qW, const float* __restrict__ kvW,
                         const float* __restrict__ projW, const float* __restrict__ srW,
                         unsigned short* __restrict__ qWs, unsigned short* __restrict__ kvWs,
                         unsigned short* __restrict__ projWs, unsigned short* __restrict__ srWs) {
    int i = blockIdx.x * 256 + threadIdx.x;
    if (i < 16384) {
        int n = i & 127, k = i >> 7;
        qWs[fragidx(n, k, 4)] = f2bf(qW[k * 128 + n]);
    } else if (i < 49152) {
        int j = i - 16384; int n = j & 255, k = j >> 8;
        kvWs[fragidx(n, k, 4)] = f2bf(kvW[k * 256 + n]);
    } else if (i < 65536) {
        int j = i - 49152; int n = j & 127, k = j >> 7;
        projWs[fragidx(n, k, 4)] = f2bf(projW[k * 128 + n]);
    } else {
        int j = i - 65536; int n = j >> 9, rem = j & 511, q = rem >> 7, c = rem & 127;
        srWs[fragidx(n, q * 128 + c, 16)] = f2bf(srW[n * 512 + c * 4 + q]);
    }
}

// ---------------------------------------------------------------------------
// x fp32 -> xsw frags [32768 rows][128 k] AND Psw conv-patch frags [8192][512]
__global__ void k_prep_x(const float* __restrict__ x, unsigned short* __restrict__ xsw,
                         unsigned short* __restrict__ Psw) {
    int i = blockIdx.x * 256 + threadIdx.x;
    int c4 = i & 31;
    int row = i >> 5;
    float4 v = *(const float4*)(x + (size_t)row * 128 + c4 * 4);
    u16x4_t o = pk4(v.x, v.y, v.z, v.w);
    int ch = c4 * 4;
    *(u16x4_t*)(xsw + fragidx(row, ch, 4)) = o;
    int b = row >> 13, n = row & 8191;
    int hf = n >> 12, rem = n & 4095;
    int y = rem >> 6, xc = rem & 63;
    int oy = y >> 1, ky = y & 1, ox = xc >> 1, kx = xc & 1;
    int q = ky * 2 + kx;
    int pos = b * 2048 + hf * 1024 + oy * 32 + ox;
    *(u16x4_t*)(Psw + fragidx(pos, q * 128 + ch, 16)) = o;
}

// ---------------------------------------------------------------------------
// Fused SR-conv + bias + LayerNorm + kv-projection.
// Block 256 (4 waves) = 32 conv rows (2 row-tiles). Wave w: row-tile w>>1,
// feature-half w&1 for the conv; wave pairs combine LN moments via LDS.
// xkv lives only in LDS; K stored transposed-orientation frags, V normal.
__global__ __launch_bounds__(256)
void k_convkv(const unsigned short* __restrict__ Psw, const unsigned short* __restrict__ srWs,
              const float* __restrict__ srb, const float* __restrict__ lnW,
              const float* __restrict__ lnB, const unsigned short* __restrict__ kvWs,
              const float* __restrict__ kvb, unsigned short* __restrict__ ksw,
              unsigned short* __restrict__ vsw) {
    const int t = threadIdx.x, w = t >> 6, lane = t & 63;
    const int col = lane & 15, quad = lane >> 4;
    const int rt_l = w >> 1, hf = w & 1;
    const int RT = blockIdx.x * 2 + rt_l;          // global row-tile (of 512)

    __shared__ unsigned short xkvs[2 * 4 * 512];   // 8 KB xkv frags
    __shared__ float lnred[4][16][2];

    // conv (transposed): acc[j] = feature-tile hf*4+j for rows RT*16+col
    f32x4_t acc[4] = {};
    {
        const unsigned short* xp = Psw + (size_t)RT * 16 * 512 + lane * 8;
        const unsigned short* wp = srWs + (size_t)hf * 4 * 16 * 512 + lane * 8;
        for (int kc = 0; kc < 16; kc++) {
            bf16x8_t xb = *(const bf16x8_t*)(xp + (size_t)kc * 512);
            #pragma unroll
            for (int j = 0; j < 4; j++) {
                bf16x8_t wf = *(const bf16x8_t*)(wp + (size_t)(j * 16 + kc) * 512);
                acc[j] = MFMA16(wf, xb, acc[j]);
            }
        }
    }
    // + bias, wave-local moments
    float s = 0.f, ss = 0.f;
    #pragma unroll
    for (int j = 0; j < 4; j++) {
        float4 bs = *(const float4*)(srb + hf * 64 + j * 16 + quad * 4);
        acc[j][0] += bs.x; acc[j][1] += bs.y; acc[j][2] += bs.z; acc[j][3] += bs.w;
        #pragma unroll
        for (int r = 0; r < 4; r++) { float v = acc[j][r]; s += v; ss += v * v; }
    }
    s += __shfl_xor(s, 16, 64);  s += __shfl_xor(s, 32, 64);
    ss += __shfl_xor(ss, 16, 64); ss += __shfl_xor(ss, 32, 64);
    if (lane < 16) { lnred[w][lane][0] = s; lnred[w][lane][1] = ss; }
    __syncthreads();
    float stot = s + lnred[w ^ 1][col][0];
    float sstot = ss + lnred[w ^ 1][col][1];
    float mean = stot * (1.0f / 128.0f);
    float var = sstot * (1.0f / 128.0f) - mean * mean;
    float rs = rsqrtf(var + LN_EPS);
    // normalize -> LDS xkv frags
    #pragma unroll
    for (int j = 0; j < 4; j++) {
        int f0 = hf * 64 + j * 16 + quad * 4;
        float4 g = *(const float4*)(lnW + f0);
        float4 be = *(const float4*)(lnB + f0);
        u16x4_t o = pk4((acc[j][0] - mean) * rs * g.x + be.x,
                        (acc[j][1] - mean) * rs * g.y + be.y,
                        (acc[j][2] - mean) * rs * g.z + be.z,
                        (acc[j][3] - mean) * rs * g.w + be.w);
        *(u16x4_t*)(xkvs + ((size_t)(rt_l * 4 + (f0 >> 5))) * 512 +
                    (((f0 >> 3) & 3) * 16 + col) * 8 + (f0 & 7)) = o;
    }
    __syncthreads();
    // kv projection: xkv frags from LDS (both row-tiles per wave)
    bf16x8_t xf[2][4];
    #pragma unroll
    for (int rt = 0; rt < 2; rt++)
        #pragma unroll
        for (int kc = 0; kc < 4; kc++)
            xf[rt][kc] = *(const bf16x8_t*)(xkvs + (size_t)(rt * 4 + kc) * 512 + lane * 8);
    // K (transposed): feature-tiles nt2 = w*2, w*2+1
    #pragma unroll
    for (int i = 0; i < 2; i++) {
        const int nt2 = w * 2 + i;
        f32x4_t aK[2] = {};
        #pragma unroll
        for (int kc = 0; kc < 4; kc++) {
            bf16x8_t wf = *(const bf16x8_t*)(kvWs + (size_t)(nt2 * 4 + kc) * 512 + lane * 8);
            aK[0] = MFMA16(wf, xf[0][kc], aK[0]);
            aK[1] = MFMA16(wf, xf[1][kc], aK[1]);
        }
        float4 bs = *(const float4*)(kvb + nt2 * 16 + quad * 4);
        #pragma unroll
        for (int rt = 0; rt < 2; rt++) {
            int p = (blockIdx.x * 2 + rt) * 16 + col;
            int m = p & 2047, bb = p >> 11;
            int bh = bb * 2 + (nt2 >> 2);
            u16x4_t o = pk4(aK[rt][0] + bs.x, aK[rt][1] + bs.y,
                            aK[rt][2] + bs.z, aK[rt][3] + bs.w);
            *(u16x4_t*)(ksw + ((size_t)(bh * 128 + (m >> 4)) * 2 + ((nt2 >> 1) & 1)) * 512 +
                        (((nt2 & 1) * 2 + (quad >> 1)) * 16 + (m & 15)) * 8 + (quad & 1) * 4) = o;
        }
    }
    // V (normal): feature-tiles nt2 = 8+w*2, +1
    #pragma unroll
    for (int i = 0; i < 2; i++) {
        const int nt2 = 8 + w * 2 + i;
        f32x4_t aV[2] = {};
        #pragma unroll
        for (int kc = 0; kc < 4; kc++) {
            bf16x8_t wf = *(const bf16x8_t*)(kvWs + (size_t)(nt2 * 4 + kc) * 512 + lane * 8);
            aV[0] = MFMA16(xf[0][kc], wf, aV[0]);
            aV[1] = MFMA16(xf[1][kc], wf, aV[1]);
        }
        int fv = (nt2 - 8) * 16 + col;
        int h = fv >> 6, dd = fv & 63;
        float bv = kvb[128 + fv];
        #pragma unroll
        for (int rt = 0; rt < 2; rt++) {
            int G = (blockIdx.x * 2 + rt) * 16 + quad * 4;
            int bb = G >> 11, m0 = G & 2047;
            int bh = bb * 2 + h;
            u16x4_t o = pk4(aV[rt][0] + bv, aV[rt][1] + bv,
                            aV[rt][2] + bv, aV[rt][3] + bv);
            *(u16x4_t*)(vsw + ((size_t)((bh * 4 + (dd >> 4)) * 64 + (m0 >> 5))) * 512 +
                        (((m0 >> 3) & 3) * 16 + (dd & 15)) * 8 + (m0 & 7)) = o;
        }
    }
}

// ---------------------------------------------------------------------------
// Fused q-proj + attention + out-proj.
// Block 512 (8 waves = 4 q-tiles x 2 heads), 64 queries/block, both heads.
// grid (64, 2 mod, 4 b) = 512 blocks -> 4 waves/SIMD.
__global__ __launch_bounds__(512)
void k_attn_f(const unsigned short* __restrict__ xsw, const unsigned short* __restrict__ qWs,
              const float* __restrict__ qb, const unsigned short* __restrict__ ksw,
              const unsigned short* __restrict__ vsw, const unsigned short* __restrict__ projWs,
              const float* __restrict__ projb, float* __restrict__ out) {
    const int blkx = blockIdx.x, mod = blockIdx.y, b = blockIdx.z;
    const int t = threadIdx.x, w = t >> 6, lane = t & 63;
    const int col = lane & 15, quad = lane >> 4;
    const int qt = w & 3, h = w >> 2;
    const int bh = b * 2 + h;

    __shared__ unsigned short qls[16 * 512];   // Q frags, reused as O frags
    __shared__ unsigned short pp[8][16][72];

    // ---- q-proj: Q^T for this wave's 16 queries, head h (wave-local)
    {
        const int qtile_g = b * 512 + mod * 256 + blkx * 4 + qt;
        f32x4_t acc[4] = {};
        const unsigned short* xp = xsw + (size_t)qtile_g * 4 * 512 + lane * 8;
        const unsigned short* wp = qWs + (size_t)h * 16 * 512 + lane * 8;
        #pragma unroll
        for (int kc = 0; kc < 4; kc++) {
            bf16x8_t xb = *(const bf16x8_t*)(xp + (size_t)kc * 512);
            #pragma unroll
            for (int j = 0; j < 4; j++) {
                bf16x8_t wf = *(const bf16x8_t*)(wp + (size_t)(j * 4 + kc) * 512);
                acc[j] = MFMA16(wf, xb, acc[j]);
            }
        }
        const float sc = 0.125f * 1.44269504089f;   // scale * log2(e)
        #pragma unroll
        for (int j = 0; j < 4; j++) {
            float4 bs = *(const float4*)(qb + h * 64 + j * 16 + quad * 4);
            u16x4_t o = pk4((acc[j][0] + bs.x) * sc, (acc[j][1] + bs.y) * sc,
                            (acc[j][2] + bs.z) * sc, (acc[j][3] + bs.w) * sc);
            *(u16x4_t*)(qls + ((size_t)((h * 4 + qt) * 2 + (j >> 1))) * 512 +
                        (((j & 1) * 2 + (quad >> 1)) * 16 + col) * 8 + (quad & 1) * 4) = o;
        }
    }
    const bf16x8_t qf0 = *(const bf16x8_t*)(qls + (size_t)((h * 4 + qt) * 2 + 0) * 512 + lane * 8);
    const bf16x8_t qf1 = *(const bf16x8_t*)(qls + (size_t)((h * 4 + qt) * 2 + 1) * 512 + lane * 8);

    // ---- attention over the other modality's 1024 keys
    const unsigned short* kp0 = ksw + ((size_t)(bh * 128 + (1 - mod) * 64) * 2) * 512 + lane * 8;
    const unsigned short* vp0 = vsw + ((size_t)(bh * 4) * 64 + (1 - mod) * 32) * 512 + lane * 8;
    const bf16x8_t ones = { 0x3F80, 0x3F80, 0x3F80, 0x3F80,
                            0x3F80, 0x3F80, 0x3F80, 0x3F80 };
    f32x4_t O[4] = {};
    f32x4_t accl = {};

    for (int kt = 0; kt < 16; kt++) {
        bf16x8_t kf[8], vf[8];
        #pragma unroll
        for (int i = 0; i < 8; i++)
            kf[i] = *(const bf16x8_t*)(kp0 + (size_t)(kt * 8 + i) * 512);
        #pragma unroll
        for (int dt = 0; dt < 4; dt++) {
            vf[dt * 2 + 0] = *(const bf16x8_t*)(vp0 + ((size_t)dt * 64 + kt * 2 + 0) * 512);
            vf[dt * 2 + 1] = *(const bf16x8_t*)(vp0 + ((size_t)dt * 64 + kt * 2 + 1) * 512);
        }
        f32x4_t ST[4];
        #pragma unroll
        for (int nb = 0; nb < 4; nb++) {
            f32x4_t sA = {};
            sA = MFMA16(kf[nb * 2 + 0], qf0, sA);
            sA = MFMA16(kf[nb * 2 + 1], qf1, sA);
            ST[nb] = sA;
        }
        #pragma unroll
        for (int nb = 0; nb < 4; nb++) {
            u16x4_t pk = pk4(exp2f(ST[nb][0]), exp2f(ST[nb][1]),
                             exp2f(ST[nb][2]), exp2f(ST[nb][3]));
            *(u16x4_t*)(&pp[w][col][nb * 16 + quad * 4]) = pk;
        }
        bf16x8_t pb0 = *(const bf16x8_t*)(&pp[w][col][quad * 8]);
        bf16x8_t pb1 = *(const bf16x8_t*)(&pp[w][col][32 + quad * 8]);
        accl = MFMA16(ones, pb0, accl);
        accl = MFMA16(ones, pb1, accl);
        #pragma unroll
        for (int dt = 0; dt < 4; dt++) {
            O[dt] = MFMA16(vf[dt * 2 + 0], pb0, O[dt]);
            O[dt] = MFMA16(vf[dt * 2 + 1], pb1, O[dt]);
        }
    }
    __syncthreads();   // all waves done reading Q region
    // ---- stage O (scaled by 1/l) into LDS as proj B-frags
    {
        float rl = 1.0f / accl[0];
        #pragma unroll
        for (int dt = 0; dt < 4; dt++) {
            u16x4_t o = pk4(O[dt][0] * rl, O[dt][1] * rl, O[dt][2] * rl, O[dt][3] * rl);
            *(u16x4_t*)(qls + ((size_t)(qt * 4 + h * 2 + (dt >> 1))) * 512 +
                        (((dt & 1) * 2 + (quad >> 1)) * 16 + col) * 8 + (quad & 1) * 4) = o;
        }
    }
    __syncthreads();
    // ---- out-proj: wave (qt2 = w&3, nhalf = w>>2) -> fp32 out
    {
        const int qt2 = w & 3, nh = w >> 2;
        f32x4_t acc[4] = {};
        const unsigned short* wp = projWs + (size_t)nh * 16 * 512 + lane * 8;
        #pragma unroll
        for (int kc = 0; kc < 4; kc++) {
            bf16x8_t ob = *(const bf16x8_t*)(qls + (size_t)(qt2 * 4 + kc) * 512 + lane * 8);
            #pragma unroll
            for (int j = 0; j < 4; j++) {
                bf16x8_t wf = *(const bf16x8_t*)(wp + (size_t)(j * 4 + kc) * 512);
                acc[j] = MFMA16(wf, ob, acc[j]);
            }
        }
        const int n = b * 8192 + mod * 4096 + blkx * 64 + qt2 * 16 + col;
        #pragma unroll
        for (int j = 0; j < 4; j++) {
            int f0 = nh * 64 + j * 16 + quad * 4;
            float4 bs = *(const float4*)(projb + f0);
            float4 o = { acc[j][0] + bs.x, acc[j][1] + bs.y,
                         acc[j][2] + bs.z, acc[j][3] + bs.w };
            *(float4*)(out + (size_t)n * 128 + f0) = o;
        }
    }
}

// ---------------------------------------------------------------------------
extern "C" void kernel_launch(void* const* d_in, const int* in_sizes, int n_in,
                              void* d_out, int out_size, void* d_ws, size_t ws_size,
                              hipStream_t stream) {
    const float* x     = (const float*)d_in[0];
    const float* qW    = (const float*)d_in[1];
    const float* qb    = (const float*)d_in[2];
    const float* kvW   = (const float*)d_in[3];
    const float* kvb   = (const float*)d_in[4];
    const float* projW = (const float*)d_in[5];
    const float* projb = (const float*)d_in[6];
    const float* srW   = (const float*)d_in[7];
    const float* srb   = (const float*)d_in[8];
    const float* lnW   = (const float*)d_in[9];
    const float* lnB   = (const float*)d_in[10];

    char* ws = (char*)d_ws;
    unsigned short* qWs    = (unsigned short*)(ws + 0);         // 32 KB
    unsigned short* kvWs   = (unsigned short*)(ws + 32768);     // 64 KB
    unsigned short* projWs = (unsigned short*)(ws + 98304);     // 32 KB
    unsigned short* srWs   = (unsigned short*)(ws + 131072);    // 128 KB
    unsigned short* xsw    = (unsigned short*)(ws + 262144);    // 8 MB
    unsigned short* Psw    = (unsigned short*)(ws + 8650752);   // 8 MB
    unsigned short* ksw    = (unsigned short*)(ws + 17039360);  // 2 MB
    unsigned short* vsw    = (unsigned short*)(ws + 19136512);  // 2 MB

    k_prep_w<<<dim3(512), dim3(256), 0, stream>>>(qW, kvW, projW, srW,
                                                  qWs, kvWs, projWs, srWs);
    k_prep_x<<<dim3(4096), dim3(256), 0, stream>>>(x, xsw, Psw);
    k_convkv<<<dim3(256), dim3(256), 0, stream>>>(Psw, srWs, srb, lnW, lnB,
                                                  kvWs, kvb, ksw, vsw);
    k_attn_f<<<dim3(64, 2, 4), dim3(512), 0, stream>>>(xsw, qWs, qb, ksw, vsw,
                                                       projWs, projb, (float*)d_out);
}

// Round 6
// 146.830 us; speedup vs baseline: 1.2975x; 1.0155x over previous
//
#include <hip/hip_runtime.h>
#include <hip/hip_bf16.h>

#define LN_EPS 1e-5f

typedef __attribute__((ext_vector_type(8))) short bf16x8_t;
typedef __attribute__((ext_vector_type(4))) short bf16x4_t;
typedef __attribute__((ext_vector_type(4))) float f32x4_t;
typedef __attribute__((ext_vector_type(4))) unsigned short u16x4_t;

#define MFMA32(a, b, c) __builtin_amdgcn_mfma_f32_16x16x32_bf16(a, b, c, 0, 0, 0)
#define MFMA16(a, b, c) __builtin_amdgcn_mfma_f32_16x16x16bf16_1k(a, b, c, 0, 0, 0)

__device__ inline unsigned short f2bf(float f) {
    union { float f; unsigned int u; } v; v.f = f;
    unsigned int r = v.u + 0x7fffu + ((v.u >> 16) & 1u);
    return (unsigned short)(r >> 16);
}

__device__ inline u16x4_t pk4(float a, float b, float c, float d) {
    union { u16x4_t v; __hip_bfloat162 h[2]; } u;
    u.h[0] = __float22bfloat162_rn(float2{a, b});
    u.h[1] = __float22bfloat162_rn(float2{c, d});
    return u.v;
}
__device__ inline bf16x4_t pk4b(float a, float b, float c, float d) {
    union { bf16x4_t v; __hip_bfloat162 h[2]; } u;
    u.h[0] = __float22bfloat162_rn(float2{a, b});
    u.h[1] = __float22bfloat162_rn(float2{c, d});
    return u.v;
}
__device__ inline bf16x8_t pk8(float4 a, float4 b) {
    union { bf16x8_t v; __hip_bfloat162 h[4]; } u;
    u.h[0] = __float22bfloat162_rn(float2{a.x, a.y});
    u.h[1] = __float22bfloat162_rn(float2{a.z, a.w});
    u.h[2] = __float22bfloat162_rn(float2{b.x, b.y});
    u.h[3] = __float22bfloat162_rn(float2{b.z, b.w});
    return u.v;
}

// Fragment-layout index for [ROWS][KD] stored as MFMA fragments:
// tile (row>>4, k>>5) = 512 contiguous u16; lane=((k>>3)&3)*16+(row&15), j=k&7.
__device__ inline size_t fragidx(int row, int k, int KC) {
    return ((size_t)((row >> 4) * KC + (k >> 5))) * 512 +
           (((k >> 3) & 3) * 16 + (row & 15)) * 8 + (k & 7);
}

// ---------------------------------------------------------------------------
__global__ void k_prep_w(const float* __restrict__ qW, const float* __restrict__ kvW,
                         const float* __restrict__ projW, const float* __restrict__ srW,
                         unsigned short* __restrict__ qWs, unsigned short* __restrict__ kvWs,
                         unsigned short* __restrict__ projWs, unsigned short* __restrict__ srWs) {
    int i = blockIdx.x * 256 + threadIdx.x;
    if (i < 16384) {
        int n = i & 127, k = i >> 7;
        qWs[fragidx(n, k, 4)] = f2bf(qW[k * 128 + n]);
    } else if (i < 49152) {
        int j = i - 16384; int n = j & 255, k = j >> 8;
        kvWs[fragidx(n, k, 4)] = f2bf(kvW[k * 256 + n]);
    } else if (i < 65536) {
        int j = i - 49152; int n = j & 127, k = j >> 7;
        projWs[fragidx(n, k, 4)] = f2bf(projW[k * 128 + n]);
    } else {
        int j = i - 65536; int n = j >> 9, rem = j & 511, q = rem >> 7, c = rem & 127;
        srWs[fragidx(n, q * 128 + c, 16)] = f2bf(srW[n * 512 + c * 4 + q]);
    }
}

// ---------------------------------------------------------------------------
// x fp32 -> Psw conv-patch frags [8192 pos][512 k] (bf16)
__global__ void k_prep_x(const float* __restrict__ x, unsigned short* __restrict__ Psw) {
    int i = blockIdx.x * 256 + threadIdx.x;
    int c4 = i & 31;
    int row = i >> 5;
    float4 v = *(const float4*)(x + (size_t)row * 128 + c4 * 4);
    u16x4_t o = pk4(v.x, v.y, v.z, v.w);
    int ch = c4 * 4;
    int b = row >> 13, n = row & 8191;
    int hf = n >> 12, rem = n & 4095;
    int y = rem >> 6, xc = rem & 63;
    int oy = y >> 1, ky = y & 1, ox = xc >> 1, kx = xc & 1;
    int q = ky * 2 + kx;
    int pos = b * 2048 + hf * 1024 + oy * 32 + ox;
    *(u16x4_t*)(Psw + fragidx(pos, q * 128 + ch, 16)) = o;
}

// ---------------------------------------------------------------------------
// Fused SR-conv + bias + LayerNorm + kv-projection.
// Grid 512 (1 row-tile = 16 positions per block), block 256 = 4 waves.
// Conv: wave w computes feature-tiles {2w, 2w+1} (transposed: D[feat][pos]).
// LN moments combined across quads (shfl) and waves (LDS). xkv lives in LDS.
// K -> ksw A-frags; V -> vls K16-B-operand layout [bh][kt32][dt4][np2][512].
__global__ __launch_bounds__(256)
void k_convkv(const unsigned short* __restrict__ Psw, const unsigned short* __restrict__ srWs,
              const float* __restrict__ srb, const float* __restrict__ lnW,
              const float* __restrict__ lnB, const unsigned short* __restrict__ kvWs,
              const float* __restrict__ kvb, unsigned short* __restrict__ ksw,
              unsigned short* __restrict__ vls) {
    const int t = threadIdx.x, w = t >> 6, lane = t & 63;
    const int col = lane & 15, quad = lane >> 4;
    const int RT = blockIdx.x;                 // row-tile 0..511

    __shared__ unsigned short xs[4 * 512];     // xkv frags for this row-tile
    __shared__ float lnred[4][16][2];

    // conv (transposed)
    f32x4_t acc[2] = {};
    {
        const unsigned short* xp = Psw + (size_t)RT * 16 * 512 + lane * 8;
        const unsigned short* wp = srWs + lane * 8;
        for (int kc = 0; kc < 16; kc++) {
            bf16x8_t xb = *(const bf16x8_t*)(xp + (size_t)kc * 512);
            #pragma unroll
            for (int jj = 0; jj < 2; jj++) {
                bf16x8_t wf = *(const bf16x8_t*)(wp + (size_t)((w * 2 + jj) * 16 + kc) * 512);
                acc[jj] = MFMA32(wf, xb, acc[jj]);
            }
        }
    }
    // + bias, moments
    float s = 0.f, ss = 0.f;
    #pragma unroll
    for (int jj = 0; jj < 2; jj++) {
        float4 bs = *(const float4*)(srb + (w * 2 + jj) * 16 + quad * 4);
        acc[jj][0] += bs.x; acc[jj][1] += bs.y; acc[jj][2] += bs.z; acc[jj][3] += bs.w;
        #pragma unroll
        for (int r = 0; r < 4; r++) { float v = acc[jj][r]; s += v; ss += v * v; }
    }
    s += __shfl_xor(s, 16, 64);  s += __shfl_xor(s, 32, 64);
    ss += __shfl_xor(ss, 16, 64); ss += __shfl_xor(ss, 32, 64);
    if (lane < 16) { lnred[w][lane][0] = s; lnred[w][lane][1] = ss; }
    __syncthreads();
    float stot = 0.f, sstot = 0.f;
    #pragma unroll
    for (int ww = 0; ww < 4; ww++) { stot += lnred[ww][col][0]; sstot += lnred[ww][col][1]; }
    float mean = stot * (1.0f / 128.0f);
    float var = sstot * (1.0f / 128.0f) - mean * mean;
    float rs = rsqrtf(var + LN_EPS);
    #pragma unroll
    for (int jj = 0; jj < 2; jj++) {
        int f0 = (w * 2 + jj) * 16 + quad * 4;
        float4 g = *(const float4*)(lnW + f0);
        float4 be = *(const float4*)(lnB + f0);
        u16x4_t o = pk4((acc[jj][0] - mean) * rs * g.x + be.x,
                        (acc[jj][1] - mean) * rs * g.y + be.y,
                        (acc[jj][2] - mean) * rs * g.z + be.z,
                        (acc[jj][3] - mean) * rs * g.w + be.w);
        *(u16x4_t*)(xs + ((size_t)(f0 >> 5)) * 512 +
                    (((f0 >> 3) & 3) * 16 + col) * 8 + (f0 & 7)) = o;
    }
    __syncthreads();
    bf16x8_t xf[4];
    #pragma unroll
    for (int kc = 0; kc < 4; kc++)
        xf[kc] = *(const bf16x8_t*)(xs + (size_t)kc * 512 + lane * 8);
    const int p0 = RT * 16;
    const int bb = p0 >> 11;
    // K (transposed): feature-tiles {2w, 2w+1}
    #pragma unroll
    for (int jj = 0; jj < 2; jj++) {
        const int nt = w * 2 + jj;
        f32x4_t aK = {};
        #pragma unroll
        for (int kc = 0; kc < 4; kc++) {
            bf16x8_t wf = *(const bf16x8_t*)(kvWs + (size_t)(nt * 4 + kc) * 512 + lane * 8);
            aK = MFMA32(wf, xf[kc], aK);
        }
        float4 bs = *(const float4*)(kvb + nt * 16 + quad * 4);
        int m = (p0 + col) & 2047;
        int bh = bb * 2 + (nt >> 2);
        int d0 = (nt & 3) * 16 + quad * 4;
        u16x4_t o = pk4(aK[0] + bs.x, aK[1] + bs.y, aK[2] + bs.z, aK[3] + bs.w);
        *(u16x4_t*)(ksw + ((size_t)(bh * 128 + (m >> 4)) * 2 + (d0 >> 5)) * 512 +
                    (((d0 >> 3) & 3) * 16 + (m & 15)) * 8 + (d0 & 7)) = o;
    }
    // V (normal): feature-tiles {2w, 2w+1} of V's 8 -> vls K16-B layout
    #pragma unroll
    for (int jj = 0; jj < 2; jj++) {
        const int nt = w * 2 + jj;
        f32x4_t aV = {};
        #pragma unroll
        for (int kc = 0; kc < 4; kc++) {
            bf16x8_t wf = *(const bf16x8_t*)(kvWs + (size_t)((8 + nt) * 4 + kc) * 512 + lane * 8);
            aV = MFMA32(xf[kc], wf, aV);
        }
        int fv = nt * 16 + col;
        int h = fv >> 6, dd = fv & 63;
        float bv = kvb[128 + fv];
        int m0 = (p0 + quad * 4) & 2047;
        int bh = bb * 2 + h;
        int kt = m0 >> 6, nb = (m0 >> 4) & 3;
        u16x4_t o = pk4(aV[0] + bv, aV[1] + bv, aV[2] + bv, aV[3] + bv);
        *(u16x4_t*)(vls + (((size_t)(bh * 32 + kt) * 4 + (dd >> 4)) * 2 + (nb >> 1)) * 512 +
                    (quad * 16 + (dd & 15)) * 8 + (nb & 1) * 4) = o;
    }
}

// ---------------------------------------------------------------------------
// Fused q-proj + attention + out-proj. LDS-free K-loop:
// S^T = K·Q^T (C-layout row=quad*4+r == K16 A-layout k=quad*4+j), so
// exp->pk4b of S registers directly feeds PV (A=P, B=V-K16-frags) and the
// ones-B l-accumulate. Block 256 = 4 waves (qg,h), 32 q/wave; grid (64,2,4).
__global__ __launch_bounds__(256)
void k_attn_f2(const float* __restrict__ x, const unsigned short* __restrict__ qWs,
               const float* __restrict__ qb, const unsigned short* __restrict__ ksw,
               const unsigned short* __restrict__ vls, const unsigned short* __restrict__ projWs,
               const float* __restrict__ projb, float* __restrict__ out) {
    const int blkx = blockIdx.x, mod = blockIdx.y, b = blockIdx.z;
    const int t = threadIdx.x, w = t >> 6, lane = t & 63;
    const int col = lane & 15, quad = lane >> 4;
    const int qg = w & 1, h = w >> 1;
    const int bh = b * 2 + h;
    const int qbase = mod * 4096 + blkx * 64 + qg * 32;   // within batch b

    __shared__ unsigned short sbuf[64 * 136];   // Q frags (16KB) then O rows

    // ---- q-proj: Q B-frags (scale*log2e folded), wave-local staging
    unsigned short* qarea = sbuf + w * 2048;
    const float sc = 0.125f * 1.44269504089f;
    #pragma unroll
    for (int qt = 0; qt < 2; qt++) {
        const float* xrow = x + ((size_t)b * 8192 + qbase + qt * 16 + col) * 128;
        f32x4_t acc[4] = {};
        #pragma unroll
        for (int kc = 0; kc < 4; kc++) {
            float4 xa = *(const float4*)(xrow + kc * 32 + quad * 8);
            float4 xb2 = *(const float4*)(xrow + kc * 32 + quad * 8 + 4);
            bf16x8_t xf = pk8(xa, xb2);
            #pragma unroll
            for (int j = 0; j < 4; j++) {
                bf16x8_t wf = *(const bf16x8_t*)(qWs + (size_t)((h * 4 + j) * 4 + kc) * 512 + lane * 8);
                acc[j] = MFMA32(wf, xf, acc[j]);
            }
        }
        #pragma unroll
        for (int j = 0; j < 4; j++) {
            float4 bs = *(const float4*)(qb + h * 64 + j * 16 + quad * 4);
            u16x4_t o = pk4((acc[j][0] + bs.x) * sc, (acc[j][1] + bs.y) * sc,
                            (acc[j][2] + bs.z) * sc, (acc[j][3] + bs.w) * sc);
            *(u16x4_t*)(qarea + ((size_t)(qt * 2 + (j >> 1))) * 512 +
                        (((j & 1) * 2 + (quad >> 1)) * 16 + col) * 8 + (quad & 1) * 4) = o;
        }
    }
    bf16x8_t qf[2][2];
    #pragma unroll
    for (int qt = 0; qt < 2; qt++)
        #pragma unroll
        for (int kc = 0; kc < 2; kc++)
            qf[qt][kc] = *(const bf16x8_t*)(qarea + (size_t)(qt * 2 + kc) * 512 + lane * 8);
    __syncthreads();   // Q regs loaded everywhere; sbuf free for O staging

    const unsigned short* kp0 =
        ksw + ((size_t)(bh * 128 + (1 - mod) * 64) * 2) * 512 + lane * 8;
    const unsigned short* vp0 =
        vls + ((size_t)(bh * 32 + (1 - mod) * 16) * 8) * 512 + lane * 8;
    const bf16x4_t ones4 = { 0x3F80, 0x3F80, 0x3F80, 0x3F80 };

    f32x4_t O[2][4] = {};
    f32x4_t accl[2] = {};

    for (int kt = 0; kt < 16; kt++) {
        // K A-frags (8 b128) and V K16-B pairs (8 b128) — contiguous streams
        bf16x8_t kf[8];
        #pragma unroll
        for (int i = 0; i < 8; i++)
            kf[i] = *(const bf16x8_t*)(kp0 + (size_t)(kt * 8 + i) * 512);
        union { bf16x8_t v8; bf16x4_t v4[2]; } vf[8];
        #pragma unroll
        for (int i = 0; i < 8; i++)
            vf[i].v8 = *(const bf16x8_t*)(vp0 + (size_t)(kt * 8 + i) * 512);
        // S^T = K·Q^T
        f32x4_t ST[2][4];
        #pragma unroll
        for (int qt = 0; qt < 2; qt++)
            #pragma unroll
            for (int nb = 0; nb < 4; nb++) {
                f32x4_t sA = {};
                sA = MFMA32(kf[nb * 2 + 0], qf[qt][0], sA);
                sA = MFMA32(kf[nb * 2 + 1], qf[qt][1], sA);
                ST[qt][nb] = sA;
            }
        // exp2 -> P in K16 A-operand registers (no LDS!)
        bf16x4_t pa[2][4];
        #pragma unroll
        for (int qt = 0; qt < 2; qt++)
            #pragma unroll
            for (int nb = 0; nb < 4; nb++)
                pa[qt][nb] = pk4b(exp2f(ST[qt][nb][0]), exp2f(ST[qt][nb][1]),
                                  exp2f(ST[qt][nb][2]), exp2f(ST[qt][nb][3]));
        // l accumulate (B=ones) and O += P·V
        #pragma unroll
        for (int qt = 0; qt < 2; qt++) {
            #pragma unroll
            for (int nb = 0; nb < 4; nb++) {
                accl[qt] = MFMA16(pa[qt][nb], ones4, accl[qt]);
                #pragma unroll
                for (int dt = 0; dt < 4; dt++)
                    O[qt][dt] = MFMA16(pa[qt][nb], vf[dt * 2 + (nb >> 1)].v4[nb & 1], O[qt][dt]);
            }
        }
    }

    // ---- epilogue: O rows (query=quad*4+r, d=col) -> sbuf [64 q][136]
    #pragma unroll
    for (int qt = 0; qt < 2; qt++) {
        #pragma unroll
        for (int r = 0; r < 4; r++) {
            float rl = 1.0f / accl[qt][r];
            int qrow = qg * 32 + qt * 16 + quad * 4 + r;
            #pragma unroll
            for (int dt = 0; dt < 4; dt++)
                sbuf[qrow * 136 + h * 64 + dt * 16 + col] = f2bf(O[qt][dt][r] * rl);
        }
    }
    __syncthreads();
    // ---- out-proj: wave w -> q-tile w
    {
        const int qt2 = w;
        bf16x8_t ob[4];
        #pragma unroll
        for (int kc = 0; kc < 4; kc++)
            ob[kc] = *(const bf16x8_t*)(sbuf + (size_t)(qt2 * 16 + col) * 136 + kc * 32 + quad * 8);
        f32x4_t acc[8];
        #pragma unroll
        for (int j = 0; j < 8; j++) acc[j] = f32x4_t{};
        #pragma unroll
        for (int kc = 0; kc < 4; kc++)
            #pragma unroll
            for (int j = 0; j < 8; j++) {
                bf16x8_t wf = *(const bf16x8_t*)(projWs + (size_t)(j * 4 + kc) * 512 + lane * 8);
                acc[j] = MFMA32(wf, ob[kc], acc[j]);
            }
        const int n = b * 8192 + mod * 4096 + blkx * 64 + qt2 * 16 + col;
        #pragma unroll
        for (int j = 0; j < 8; j++) {
            int f0 = j * 16 + quad * 4;
            float4 bs = *(const float4*)(projb + f0);
            float4 o = { acc[j][0] + bs.x, acc[j][1] + bs.y,
                         acc[j][2] + bs.z, acc[j][3] + bs.w };
            *(float4*)(out + (size_t)n * 128 + f0) = o;
        }
    }
}

// ---------------------------------------------------------------------------
extern "C" void kernel_launch(void* const* d_in, const int* in_sizes, int n_in,
                              void* d_out, int out_size, void* d_ws, size_t ws_size,
                              hipStream_t stream) {
    const float* x     = (const float*)d_in[0];
    const float* qW    = (const float*)d_in[1];
    const float* qb    = (const float*)d_in[2];
    const float* kvW   = (const float*)d_in[3];
    const float* kvb   = (const float*)d_in[4];
    const float* projW = (const float*)d_in[5];
    const float* projb = (const float*)d_in[6];
    const float* srW   = (const float*)d_in[7];
    const float* srb   = (const float*)d_in[8];
    const float* lnW   = (const float*)d_in[9];
    const float* lnB   = (const float*)d_in[10];

    char* ws = (char*)d_ws;
    unsigned short* qWs    = (unsigned short*)(ws + 0);         // 32 KB
    unsigned short* kvWs   = (unsigned short*)(ws + 32768);     // 64 KB
    unsigned short* projWs = (unsigned short*)(ws + 98304);     // 32 KB
    unsigned short* srWs   = (unsigned short*)(ws + 131072);    // 128 KB
    unsigned short* Psw    = (unsigned short*)(ws + 262144);    // 8 MB
    unsigned short* ksw    = (unsigned short*)(ws + 8650752);   // 2 MB
    unsigned short* vls    = (unsigned short*)(ws + 10747904);  // 2 MB

    k_prep_w<<<dim3(512), dim3(256), 0, stream>>>(qW, kvW, projW, srW,
                                                  qWs, kvWs, projWs, srWs);
    k_prep_x<<<dim3(4096), dim3(256), 0, stream>>>(x, Psw);
    k_convkv<<<dim3(512), dim3(256), 0, stream>>>(Psw, srWs, srb, lnW, lnB,
                                                  kvWs, kvb, ksw, vls);
    k_attn_f2<<<dim3(64, 2, 4), dim3(256), 0, stream>>>(x, qWs, qb, ksw, vls,
                                                        projWs, projb, (float*)d_out);
}